// Round 1
// baseline (350.435 us; speedup 1.0000x reference)
//
#include <hip/hip_runtime.h>
#include <hip/hip_bf16.h>
#include <hip/hip_cooperative_groups.h>
#include <math.h>

namespace cg = cooperative_groups;

#define LRELU_ALPHA 0.2f

constexpr int B_ = 8;
constexpr int N_ = 2048;
constexpr int M_ = B_ * N_;      // 16384 rows total
constexpr int SEG = 32;          // ranks per segment for the vector scans
constexpr int NSEG = N_ / SEG;   // 64 segments per batch

// ---------------------------------------------------------------------------
// Single cooperative kernel: grid = 256 blocks x 512 threads, 4 grid syncs.
// P1 gemm+scores | P2 counting-rank | P3 segment sums | P4 prefix/suffix |
// P5 output.
// ---------------------------------------------------------------------------
__global__ __launch_bounds__(512) void k_fused(
    const float* __restrict__ text, const float* __restrict__ W,
    const float* __restrict__ a,
    float* __restrict__ h, float* __restrict__ s1, float* __restrict__ s2,
    float* __restrict__ eN0, float* __restrict__ eP0,
    int* __restrict__ perm, float* __restrict__ eNs, float* __restrict__ ePs,
    int* __restrict__ rank, float* __restrict__ ZN, float* __restrict__ ZP,
    float* __restrict__ segN, float* __restrict__ segP,
    __hip_bfloat16* __restrict__ Pre, __hip_bfloat16* __restrict__ Suf,
    float* __restrict__ out) {

    // LDS is re-used phase by phase. Max member = P1: 50.2 KB.
    __shared__ __align__(16) union {
        struct { float Ast[64 * 68]; float Ws[64 * 128]; } p1;   // A transposed (stride 68: b128-aligned, conflict-free reads)
        struct { float ls2[2048], leN[2048], leP[2048];
                 int redc[512], redm[512]; float redn[512], redp[512]; } p2;
        struct { float an[512], ap[512]; } p3;
    } sm;

    const int tid = threadIdx.x;
    const int blk = blockIdx.x;
    cg::grid_group grid = cg::this_grid();

    // ===================== P1: h = text @ W + scores =======================
    {
        const int r0 = blk * 64;                 // 64-row tile per block
        const int cx = tid & 15;                 // 16 col-groups
        const int ry = tid >> 4;                 // row-group (valid < 16 for compute)
        const int c0 = cx * 4;                   // cols [c0, c0+3]
        const int c1 = 64 + cx * 4;              // cols [c1, c1+3]
        const int rr0 = ry * 4;                  // 4 rows per thread

        float acc[4][8];
#pragma unroll
        for (int i = 0; i < 4; ++i)
#pragma unroll
            for (int j = 0; j < 8; ++j) acc[i][j] = 0.f;

        for (int kk = 0; kk < 128; kk += 64) {
            // Stage A transposed: Ast[k][r], coalesced global reads.
            for (int idx = tid; idx < 64 * 64; idx += 512) {
                int r = idx >> 6, k = idx & 63;
                sm.p1.Ast[k * 68 + r] = text[(size_t)(r0 + r) * 128 + kk + k];
            }
            // Stage W row-major (linear, coalesced).
            for (int idx = tid; idx < 64 * 128; idx += 512) {
                int k = idx >> 7, f = idx & 127;
                sm.p1.Ws[k * 128 + f] = W[(kk + k) * 128 + f];
            }
            __syncthreads();
            if (tid < 256) {
#pragma unroll 16
                for (int k = 0; k < 64; ++k) {
                    // A fragment: 4 rows, one b128 (16B-aligned, conflict-free)
                    float4 av = *(const float4*)&sm.p1.Ast[k * 68 + rr0];
                    // W fragments: 16B stride across cx -> conflict-free b128s
                    float4 w0 = *(const float4*)&sm.p1.Ws[k * 128 + c0];
                    float4 w1 = *(const float4*)&sm.p1.Ws[k * 128 + c1];
                    const float avv[4] = {av.x, av.y, av.z, av.w};
#pragma unroll
                    for (int i = 0; i < 4; ++i) {
                        acc[i][0] += avv[i] * w0.x; acc[i][1] += avv[i] * w0.y;
                        acc[i][2] += avv[i] * w0.z; acc[i][3] += avv[i] * w0.w;
                        acc[i][4] += avv[i] * w1.x; acc[i][5] += avv[i] * w1.y;
                        acc[i][6] += avv[i] * w1.z; acc[i][7] += avv[i] * w1.w;
                    }
                }
            }
            __syncthreads();
        }

        if (tid < 256) {
            float4 a1lo = *(const float4*)&a[c0];
            float4 a1hi = *(const float4*)&a[c1];
            float4 a2lo = *(const float4*)&a[128 + c0];
            float4 a2hi = *(const float4*)&a[128 + c1];
#pragma unroll
            for (int i = 0; i < 4; ++i) {
                const int row = r0 + rr0 + i;
                float4 o0 = {acc[i][0], acc[i][1], acc[i][2], acc[i][3]};
                float4 o1 = {acc[i][4], acc[i][5], acc[i][6], acc[i][7]};
                *(float4*)&h[(size_t)row * 128 + c0] = o0;
                *(float4*)&h[(size_t)row * 128 + c1] = o1;

                float p1 = o0.x*a1lo.x + o0.y*a1lo.y + o0.z*a1lo.z + o0.w*a1lo.w
                         + o1.x*a1hi.x + o1.y*a1hi.y + o1.z*a1hi.z + o1.w*a1hi.w;
                float p2 = o0.x*a2lo.x + o0.y*a2lo.y + o0.z*a2lo.z + o0.w*a2lo.w
                         + o1.x*a2hi.x + o1.y*a2hi.y + o1.z*a2hi.z + o1.w*a2hi.w;
#pragma unroll
                for (int off = 8; off >= 1; off >>= 1) {
                    p1 += __shfl_xor(p1, off);
                    p2 += __shfl_xor(p2, off);
                }
                if (cx == 0) {
                    s1[row] = p1;
                    s2[row] = p2;
                    eN0[row] = expf(LRELU_ALPHA * p2);
                    eP0[row] = expf(p2);
                }
            }
        }
    }
    grid.sync();

    // ===================== P2: counting rank ===============================
    {
        const int b  = blk >> 5;
        const int eb = blk & 31;
        const int e  = tid & 63;
        const int c  = tid >> 6;            // chunk 0..7
        {
            const float4* g2 = (const float4*)(s2  + b * 2048);
            const float4* gn = (const float4*)(eN0 + b * 2048);
            const float4* gp = (const float4*)(eP0 + b * 2048);
            ((float4*)sm.p2.ls2)[tid] = g2[tid];
            ((float4*)sm.p2.leN)[tid] = gn[tid];
            ((float4*)sm.p2.leP)[tid] = gp[tid];
        }
        __syncthreads();

        const int i  = eb * 64 + e;
        const int gi = b * 2048 + i;
        const float myS2 = sm.p2.ls2[i];
        const float thr  = -s1[gi];

        int cnt = 0, mr = 0;
        float sn = 0.f, sp = 0.f;
        const int j0 = c * 256;
#pragma unroll 4
        for (int j = j0; j < j0 + 256; j += 4) {
            float4 v  = *(const float4*)&sm.p2.ls2[j];
            float4 en = *(const float4*)&sm.p2.leN[j];
            float4 ep = *(const float4*)&sm.p2.leP[j];
#define PROC(vv, ee, pp, jj)                                             \
            { bool le = (vv) <= thr;                                     \
              cnt += le ? 1 : 0;                                         \
              sn  += le ? (ee) : 0.f;                                    \
              sp  += le ? 0.f : (pp);                                    \
              mr  += ((vv) < myS2 || ((vv) == myS2 && (jj) < i)) ? 1 : 0; }
            PROC(v.x, en.x, ep.x, j + 0)
            PROC(v.y, en.y, ep.y, j + 1)
            PROC(v.z, en.z, ep.z, j + 2)
            PROC(v.w, en.w, ep.w, j + 3)
#undef PROC
        }
        sm.p2.redc[tid] = cnt; sm.p2.redm[tid] = mr;
        sm.p2.redn[tid] = sn;  sm.p2.redp[tid] = sp;
        __syncthreads();
        if (c == 0) {
            int tc = 0, tm = 0; float tn = 0.f, tp = 0.f;
#pragma unroll
            for (int cc = 0; cc < 8; ++cc) {
                tc += sm.p2.redc[cc * 64 + e];
                tm += sm.p2.redm[cc * 64 + e];
                tn += sm.p2.redn[cc * 64 + e];
                tp += sm.p2.redp[cc * 64 + e];
            }
            perm[b * 2048 + tm] = i;
            eNs [b * 2048 + tm] = sm.p2.leN[i];
            ePs [b * 2048 + tm] = sm.p2.leP[i];
            rank[gi] = tc;
            ZN[gi] = tn;
            ZP[gi] = tp;
        }
    }
    grid.sync();

    // ===================== P3: segment sums ================================
    {
        const int task = blk * 2 + (tid >> 8);   // 512 tasks over 256 blocks
        const int st = tid & 255;
        const int f  = st & 127;
        const int hf = st >> 7;                  // half: rows 0-15 / 16-31
        const int b3 = task >> 6, s3 = task & 63;
        float an = 0.f, ap = 0.f;
        const int rb = b3 * 2048 + s3 * SEG + hf * 16;
#pragma unroll 4
        for (int r = 0; r < 16; ++r) {
            int rr = rb + r;
            float hv = h[(size_t)(b3 * 2048 + perm[rr]) * 128 + f];
            an += eNs[rr] * hv;
            ap += ePs[rr] * hv;
        }
        sm.p3.an[tid] = an; sm.p3.ap[tid] = ap;
        __syncthreads();
        if (hf == 0) {
            segN[task * 128 + f] = sm.p3.an[tid] + sm.p3.an[tid + 128];
            segP[task * 128 + f] = sm.p3.ap[tid] + sm.p3.ap[tid + 128];
        }
    }
    grid.sync();

    // ===================== P4: prefix/suffix vectors =======================
    // Forward (Pre) and backward (Suf) scans in parallel thread-halves.
    {
        const int task = blk * 2 + (tid >> 8);
        const int st = tid & 255;
        const int f  = st & 127;
        const int hf = st >> 7;
        const int b4 = task >> 6, s4 = task & 63;
        const int rbase = s4 * SEG;
        if (hf == 0) {
            float an = 0.f;
            for (int ss = 0; ss < s4; ++ss) an += segN[(b4 * NSEG + ss) * 128 + f];
#pragma unroll 4
            for (int r = 0; r < SEG; ++r) {
                int rr = b4 * 2048 + rbase + r;
                Pre[(size_t)(b4 * 2049 + rbase + r) * 128 + f] = __float2bfloat16(an);
                an += eNs[rr] * h[(size_t)(b4 * 2048 + perm[rr]) * 128 + f];
            }
            if (s4 == NSEG - 1)
                Pre[(size_t)(b4 * 2049 + 2048) * 128 + f] = __float2bfloat16(an);
        } else {
            float ap = 0.f;
            for (int ss = s4 + 1; ss < NSEG; ++ss) ap += segP[(b4 * NSEG + ss) * 128 + f];
#pragma unroll 4
            for (int r = SEG - 1; r >= 0; --r) {
                int rr = b4 * 2048 + rbase + r;
                ap += ePs[rr] * h[(size_t)(b4 * 2048 + perm[rr]) * 128 + f];
                Suf[(size_t)(b4 * 2049 + rbase + r) * 128 + f] = __float2bfloat16(ap);
            }
            if (s4 == NSEG - 1)
                Suf[(size_t)(b4 * 2049 + 2048) * 128 + f] = __float2bfloat16(0.f);
        }
    }
    grid.sync();

    // ===================== P5: output ======================================
    {
        const int lr = tid >> 7;      // 0..3: 4 rows per iteration
        const int f  = tid & 127;
#pragma unroll 2
        for (int it = 0; it < 16; ++it) {
            const int i = blk * 64 + it * 4 + lr;
            const int b = i >> 11;
            const float s1v = s1[i];
            const float E1 = expf(s1v);
            const float E2 = expf(LRELU_ALPHA * s1v);
            const int   r  = rank[i];
            const float Z  = E1 * ZP[i] + E2 * ZN[i];
            const size_t o = (size_t)(b * 2049 + r) * 128 + f;
            const float hp = (E1 * __bfloat162float(Suf[o]) + E2 * __bfloat162float(Pre[o])) / Z;
            const float x = hp + LRELU_ALPHA * h[(size_t)i * 128 + f];
            out[(size_t)i * 128 + f] = (x > 0.f) ? x : expm1f(x);
        }
    }
}

// ---------------------------------------------------------------------------
extern "C" void kernel_launch(void* const* d_in, const int* in_sizes, int n_in,
                              void* d_out, int out_size, void* d_ws, size_t ws_size,
                              hipStream_t stream) {
    const float* text = (const float*)d_in[0];
    // d_in[1] = adj : all-ones, unused by the reference math -> never read.
    const float* W = (const float*)d_in[2];
    const float* a = (const float*)d_in[3];
    float* out = (float*)d_out;

    float* p = (float*)d_ws;
    float* h    = p; p += (size_t)M_ * 128;
    float* s1   = p; p += M_;
    float* s2   = p; p += M_;
    float* eN0  = p; p += M_;
    float* eP0  = p; p += M_;
    int*   perm = (int*)p; p += M_;
    float* eNs  = p; p += M_;
    float* ePs  = p; p += M_;
    int*   rank = (int*)p; p += M_;
    float* ZN   = p; p += M_;
    float* ZP   = p; p += M_;
    float* segN = p; p += B_ * NSEG * 128;
    float* segP = p; p += B_ * NSEG * 128;
    __hip_bfloat16* Pre = (__hip_bfloat16*)p; p += (size_t)B_ * 2049 * 128 / 2;
    __hip_bfloat16* Suf = (__hip_bfloat16*)p; p += (size_t)B_ * 2049 * 128 / 2;

    void* args[] = { &text, &W, &a, &h, &s1, &s2, &eN0, &eP0,
                     &perm, &eNs, &ePs, &rank, &ZN, &ZP,
                     &segN, &segP, &Pre, &Suf, &out };
    hipLaunchCooperativeKernel((void*)k_fused, dim3(256), dim3(512),
                               args, 0, stream);
}

// Round 2
// 234.526 us; speedup vs baseline: 1.4942x; 1.4942x over previous
//
#include <hip/hip_runtime.h>
#include <hip/hip_bf16.h>
#include <math.h>

#define LRELU_ALPHA 0.2f

constexpr int B_ = 8;
constexpr int N_ = 2048;
constexpr int M_ = B_ * N_;      // 16384 rows total
constexpr int SEG = 32;          // ranks per segment for the vector scans
constexpr int NSEG = N_ / SEG;   // 64 segments per batch

// ---------------------------------------------------------------------------
// K1: h = text @ W (fp32), fused epilogue: s1 = h·a1, s2 = h·a2,
//     eN0 = exp(0.2*s2), eP0 = exp(s2).
// 256 threads, 64-row tile, 4x8 register tile.
// LDS layout: A transposed (Ast[k][r], stride 68 -> 16B-aligned, conflict-free
// b128 A-fragment reads); W row-major (16B lane stride -> 2-way = free).
// Model: 3 conflict-free ds_read_b128 per 32 FMAs -> ~7.7 us LDS-pipe bound
// (vs ~22 us for the old 4-way-conflicted layout).
// ---------------------------------------------------------------------------
__global__ __launch_bounds__(256) void k_gemm(const float* __restrict__ text,
                                              const float* __restrict__ W,
                                              const float* __restrict__ a,
                                              float* __restrict__ h,
                                              float* __restrict__ s1,
                                              float* __restrict__ s2,
                                              float* __restrict__ eN0,
                                              float* __restrict__ eP0) {
    __shared__ __align__(16) float Ast[64 * 68];   // [k][r], stride 68
    __shared__ __align__(16) float Ws[64 * 128];   // [k][f]

    const int tid = threadIdx.x;
    const int r0  = blockIdx.x * 64;
    const int cx  = tid & 15;                 // 16 col-groups
    const int ry  = tid >> 4;                 // 16 row-groups
    const int c0  = cx * 4;                   // cols [c0, c0+3]
    const int c1  = 64 + cx * 4;              // cols [c1, c1+3]
    const int rr0 = ry * 4;                   // 4 rows per thread

    float acc[4][8];
#pragma unroll
    for (int i = 0; i < 4; ++i)
#pragma unroll
        for (int j = 0; j < 8; ++j) acc[i][j] = 0.f;

    for (int kk = 0; kk < 128; kk += 64) {
        // Stage A transposed: float4 global reads, scalar LDS writes.
        for (int idx = tid; idx < 64 * 16; idx += 256) {
            int r = idx >> 4, k4 = (idx & 15) * 4;
            float4 v = *(const float4*)&text[(size_t)(r0 + r) * 128 + kk + k4];
            Ast[(k4 + 0) * 68 + r] = v.x;
            Ast[(k4 + 1) * 68 + r] = v.y;
            Ast[(k4 + 2) * 68 + r] = v.z;
            Ast[(k4 + 3) * 68 + r] = v.w;
        }
        // Stage W row-major: float4 in, float4 out (linear).
        for (int idx = tid; idx < 64 * 32; idx += 256) {
            int k = idx >> 5, f4 = (idx & 31) * 4;
            *(float4*)&Ws[k * 128 + f4] =
                *(const float4*)&W[(size_t)(kk + k) * 128 + f4];
        }
        __syncthreads();
#pragma unroll 16
        for (int k = 0; k < 64; ++k) {
            float4 av = *(const float4*)&Ast[k * 68 + rr0];   // conflict-free
            float4 w0 = *(const float4*)&Ws[k * 128 + c0];    // 2-way = free
            float4 w1 = *(const float4*)&Ws[k * 128 + c1];
            const float avv[4] = {av.x, av.y, av.z, av.w};
#pragma unroll
            for (int i = 0; i < 4; ++i) {
                acc[i][0] += avv[i] * w0.x; acc[i][1] += avv[i] * w0.y;
                acc[i][2] += avv[i] * w0.z; acc[i][3] += avv[i] * w0.w;
                acc[i][4] += avv[i] * w1.x; acc[i][5] += avv[i] * w1.y;
                acc[i][6] += avv[i] * w1.z; acc[i][7] += avv[i] * w1.w;
            }
        }
        __syncthreads();
    }

    float4 a1lo = *(const float4*)&a[c0];
    float4 a1hi = *(const float4*)&a[c1];
    float4 a2lo = *(const float4*)&a[128 + c0];
    float4 a2hi = *(const float4*)&a[128 + c1];

#pragma unroll
    for (int i = 0; i < 4; ++i) {
        const int row = r0 + rr0 + i;
        float4 o0 = {acc[i][0], acc[i][1], acc[i][2], acc[i][3]};
        float4 o1 = {acc[i][4], acc[i][5], acc[i][6], acc[i][7]};
        *(float4*)&h[(size_t)row * 128 + c0] = o0;
        *(float4*)&h[(size_t)row * 128 + c1] = o1;

        float p1 = o0.x*a1lo.x + o0.y*a1lo.y + o0.z*a1lo.z + o0.w*a1lo.w
                 + o1.x*a1hi.x + o1.y*a1hi.y + o1.z*a1hi.z + o1.w*a1hi.w;
        float p2 = o0.x*a2lo.x + o0.y*a2lo.y + o0.z*a2lo.z + o0.w*a2lo.w
                 + o1.x*a2hi.x + o1.y*a2hi.y + o1.z*a2hi.z + o1.w*a2hi.w;
#pragma unroll
        for (int off = 8; off >= 1; off >>= 1) {
            p1 += __shfl_xor(p1, off);
            p2 += __shfl_xor(p2, off);
        }
        if (cx == 0) {
            s1[row] = p1;
            s2[row] = p2;
            eN0[row] = expf(LRELU_ALPHA * p2);
            eP0[row] = expf(p2);
        }
    }
}

// ---------------------------------------------------------------------------
// K2: counting-rank kernel.
// ---------------------------------------------------------------------------
__global__ __launch_bounds__(512) void k_rank(const float* __restrict__ s2,
                                              const float* __restrict__ eN0,
                                              const float* __restrict__ eP0,
                                              const float* __restrict__ s1,
                                              int* __restrict__ perm,
                                              float* __restrict__ eNs,
                                              float* __restrict__ ePs,
                                              int* __restrict__ rank,
                                              float* __restrict__ ZN,
                                              float* __restrict__ ZP) {
    __shared__ float ls2[2048], leN[2048], leP[2048];
    __shared__ int   redc[512], redm[512];
    __shared__ float redn[512], redp[512];

    const int b  = blockIdx.x >> 5;
    const int eb = blockIdx.x & 31;
    const int tid = threadIdx.x;
    const int e = tid & 63;
    const int c = tid >> 6;            // chunk 0..7

    {
        const float4* g2 = (const float4*)(s2  + b * 2048);
        const float4* gn = (const float4*)(eN0 + b * 2048);
        const float4* gp = (const float4*)(eP0 + b * 2048);
        ((float4*)ls2)[tid] = g2[tid];
        ((float4*)leN)[tid] = gn[tid];
        ((float4*)leP)[tid] = gp[tid];
    }
    __syncthreads();

    const int i  = eb * 64 + e;
    const int gi = b * 2048 + i;
    const float myS2 = ls2[i];
    const float thr  = -s1[gi];

    int cnt = 0, mr = 0;
    float sn = 0.f, sp = 0.f;
    const int j0 = c * 256;
#pragma unroll 4
    for (int j = j0; j < j0 + 256; j += 4) {
        float4 v  = *(const float4*)&ls2[j];
        float4 en = *(const float4*)&leN[j];
        float4 ep = *(const float4*)&leP[j];
#define PROC(vv, ee, pp, jj)                                             \
        { bool le = (vv) <= thr;                                         \
          cnt += le ? 1 : 0;                                             \
          sn  += le ? (ee) : 0.f;                                        \
          sp  += le ? 0.f : (pp);                                        \
          mr  += ((vv) < myS2 || ((vv) == myS2 && (jj) < i)) ? 1 : 0; }
        PROC(v.x, en.x, ep.x, j + 0)
        PROC(v.y, en.y, ep.y, j + 1)
        PROC(v.z, en.z, ep.z, j + 2)
        PROC(v.w, en.w, ep.w, j + 3)
#undef PROC
    }
    redc[tid] = cnt; redm[tid] = mr; redn[tid] = sn; redp[tid] = sp;
    __syncthreads();
    if (c == 0) {
        int tc = 0, tm = 0; float tn = 0.f, tp = 0.f;
#pragma unroll
        for (int cc = 0; cc < 8; ++cc) {
            tc += redc[cc * 64 + e];
            tm += redm[cc * 64 + e];
            tn += redn[cc * 64 + e];
            tp += redp[cc * 64 + e];
        }
        perm[b * 2048 + tm] = i;
        eNs [b * 2048 + tm] = leN[i];
        ePs [b * 2048 + tm] = leP[i];
        rank[gi] = tc;
        ZN[gi] = tn;
        ZP[gi] = tp;
    }
}

// ---------------------------------------------------------------------------
// K3: per (batch, segment) sums of eNs*h[perm] and ePs*h[perm].
// ---------------------------------------------------------------------------
__global__ __launch_bounds__(128) void k_segsum(const float* __restrict__ h,
                                                const int* __restrict__ perm,
                                                const float* __restrict__ eNs,
                                                const float* __restrict__ ePs,
                                                float* __restrict__ segN,
                                                float* __restrict__ segP) {
    const int blk = blockIdx.x;
    const int b = blk >> 6, s = blk & 63;
    const int f = threadIdx.x;
    const int rbase = s * SEG;
    float an = 0.f, ap = 0.f;
#pragma unroll 4
    for (int r = 0; r < SEG; ++r) {
        int rr = b * 2048 + rbase + r;
        float hv = h[(size_t)(b * 2048 + perm[rr]) * 128 + f];
        an += eNs[rr] * hv;
        ap += ePs[rr] * hv;
    }
    segN[blk * 128 + f] = an;
    segP[blk * 128 + f] = ap;
}

// ---------------------------------------------------------------------------
// K4: full vector prefix/suffix arrays, stored BF16 (accumulated fp32).
// Forward (Pre) and backward (Suf) scans in SEPARATE blocks: halves the
// serial span per block and doubles occupancy vs the fused version.
//   Pre[b][r][f] = sum_{k<r}  eNs[k]*h[perm[k]][f]   (r in [0,2048])
//   Suf[b][r][f] = sum_{k>=r} ePs[k]*h[perm[k]][f]
// ---------------------------------------------------------------------------
__global__ __launch_bounds__(128) void k_prefix(const float* __restrict__ h,
                                                const int* __restrict__ perm,
                                                const float* __restrict__ eNs,
                                                const float* __restrict__ ePs,
                                                const float* __restrict__ segN,
                                                const float* __restrict__ segP,
                                                __hip_bfloat16* __restrict__ Pre,
                                                __hip_bfloat16* __restrict__ Suf) {
    const int blk  = blockIdx.x;
    const int dir  = blk & 1;
    const int task = blk >> 1;
    const int b = task >> 6, s = task & 63;
    const int f = threadIdx.x;
    const int rbase = s * SEG;

    if (dir == 0) {
        float an = 0.f;
        for (int ss = 0; ss < s; ++ss) an += segN[(b * NSEG + ss) * 128 + f];
#pragma unroll 4
        for (int r = 0; r < SEG; ++r) {
            int rr = b * 2048 + rbase + r;
            Pre[(size_t)(b * 2049 + rbase + r) * 128 + f] = __float2bfloat16(an);
            an += eNs[rr] * h[(size_t)(b * 2048 + perm[rr]) * 128 + f];
        }
        if (s == NSEG - 1)
            Pre[(size_t)(b * 2049 + 2048) * 128 + f] = __float2bfloat16(an);
    } else {
        float ap = 0.f;
        for (int ss = s + 1; ss < NSEG; ++ss) ap += segP[(b * NSEG + ss) * 128 + f];
#pragma unroll 4
        for (int r = SEG - 1; r >= 0; --r) {
            int rr = b * 2048 + rbase + r;
            ap += ePs[rr] * h[(size_t)(b * 2048 + perm[rr]) * 128 + f];
            Suf[(size_t)(b * 2049 + rbase + r) * 128 + f] = __float2bfloat16(ap);
        }
        if (s == NSEG - 1)
            Suf[(size_t)(b * 2049 + 2048) * 128 + f] = __float2bfloat16(0.f);
    }
}

// ---------------------------------------------------------------------------
// K5: out = elu(h' + 0.2 h),  h' = (E1*Suf[r] + E2*Pre[r]) / (E1*ZP + E2*ZN)
// ---------------------------------------------------------------------------
__global__ __launch_bounds__(256) void k_out(const float* __restrict__ h,
                                             const float* __restrict__ s1,
                                             const int* __restrict__ rank,
                                             const float* __restrict__ ZN,
                                             const float* __restrict__ ZP,
                                             const __hip_bfloat16* __restrict__ Pre,
                                             const __hip_bfloat16* __restrict__ Suf,
                                             float* __restrict__ out) {
    const int tid = threadIdx.x;
    const int lr = tid >> 7, f = tid & 127;
    const int i = blockIdx.x * 2 + lr;
    const int b = i >> 11;

    const float s1v = s1[i];
    const float E1 = expf(s1v);
    const float E2 = expf(LRELU_ALPHA * s1v);
    const int   r  = rank[i];
    const float Z  = E1 * ZP[i] + E2 * ZN[i];
    const size_t o = (size_t)(b * 2049 + r) * 128 + f;
    const float hp = (E1 * __bfloat162float(Suf[o]) + E2 * __bfloat162float(Pre[o])) / Z;
    const float x = hp + LRELU_ALPHA * h[(size_t)i * 128 + f];
    out[(size_t)i * 128 + f] = (x > 0.f) ? x : expm1f(x);
}

// ---------------------------------------------------------------------------
extern "C" void kernel_launch(void* const* d_in, const int* in_sizes, int n_in,
                              void* d_out, int out_size, void* d_ws, size_t ws_size,
                              hipStream_t stream) {
    const float* text = (const float*)d_in[0];
    // d_in[1] = adj : all-ones, unused by the reference math -> never read.
    const float* W = (const float*)d_in[2];
    const float* a = (const float*)d_in[3];
    float* out = (float*)d_out;

    float* p = (float*)d_ws;
    float* h    = p; p += (size_t)M_ * 128;
    float* s1   = p; p += M_;
    float* s2   = p; p += M_;
    float* eN0  = p; p += M_;
    float* eP0  = p; p += M_;
    int*   perm = (int*)p; p += M_;
    float* eNs  = p; p += M_;
    float* ePs  = p; p += M_;
    int*   rank = (int*)p; p += M_;
    float* ZN   = p; p += M_;
    float* ZP   = p; p += M_;
    float* segN = p; p += B_ * NSEG * 128;
    float* segP = p; p += B_ * NSEG * 128;
    __hip_bfloat16* Pre = (__hip_bfloat16*)p; p += (size_t)B_ * 2049 * 128 / 2;
    __hip_bfloat16* Suf = (__hip_bfloat16*)p; p += (size_t)B_ * 2049 * 128 / 2;

    hipLaunchKernelGGL(k_gemm,   dim3(M_ / 64),       dim3(256), 0, stream,
                       text, W, a, h, s1, s2, eN0, eP0);
    hipLaunchKernelGGL(k_rank,   dim3(B_ * 32),       dim3(512), 0, stream,
                       s2, eN0, eP0, s1, perm, eNs, ePs, rank, ZN, ZP);
    hipLaunchKernelGGL(k_segsum, dim3(B_ * NSEG),     dim3(128), 0, stream,
                       h, perm, eNs, ePs, segN, segP);
    hipLaunchKernelGGL(k_prefix, dim3(B_ * NSEG * 2), dim3(128), 0, stream,
                       h, perm, eNs, ePs, segN, segP, Pre, Suf);
    hipLaunchKernelGGL(k_out,    dim3(M_ / 2),        dim3(256), 0, stream,
                       h, s1, rank, ZN, ZP, Pre, Suf, out);
}